// Round 6
// baseline (1123.016 us; speedup 1.0000x reference)
//
#include <hip/hip_runtime.h>

#define IGNORE_INDEX (-100)
#define VOCAB 32000
#define DDIM  2048      /* K in elements; == bytes per row in fp8 */
#define MTOK  8192      /* B*S = 4*2048 */

#define BM 256
#define BN 256
#define BK 128          /* fp8 elems (bytes) per K-tile */
#define NKT (DDIM / BK) /* 16 K-tiles */

#define WSCALE 32.0f
#define HSCALE 8.0f
#define INVSCALE (1.0f / 256.0f)
#define SCALE_ONE 0x7F7F7F7F  /* e8m0 1.0 in every byte */

#define WBLK ((VOCAB * DDIM) / (256 * 16))   /* 16000 */
#define HBLK ((MTOK * DDIM) / (256 * 16))    /*  4096 */
#define ZBLK ((2 * MTOK * 4) / (256 * 16))   /*    16: zero sumexp+tgtlogit */

typedef float f32x4 __attribute__((ext_vector_type(4)));
typedef int   i32x8 __attribute__((ext_vector_type(8)));
typedef unsigned char uchar_t;

// ---------------- fp32 -> fp8 e4m3 (OCP, RNE via HW cvt), 16 elems/thread ----
__device__ __forceinline__ void cvt16(const float4* __restrict__ src,
                                      int4* __restrict__ dst, float scale,
                                      size_t i) {
    float4 a = src[4 * i], b = src[4 * i + 1], c = src[4 * i + 2], d = src[4 * i + 3];
    int4 o;
    int v;
    v = 0;
    v = __builtin_amdgcn_cvt_pk_fp8_f32(a.x * scale, a.y * scale, v, false);
    v = __builtin_amdgcn_cvt_pk_fp8_f32(a.z * scale, a.w * scale, v, true);
    o.x = v;
    v = 0;
    v = __builtin_amdgcn_cvt_pk_fp8_f32(b.x * scale, b.y * scale, v, false);
    v = __builtin_amdgcn_cvt_pk_fp8_f32(b.z * scale, b.w * scale, v, true);
    o.y = v;
    v = 0;
    v = __builtin_amdgcn_cvt_pk_fp8_f32(c.x * scale, c.y * scale, v, false);
    v = __builtin_amdgcn_cvt_pk_fp8_f32(c.z * scale, c.w * scale, v, true);
    o.z = v;
    v = 0;
    v = __builtin_amdgcn_cvt_pk_fp8_f32(d.x * scale, d.y * scale, v, false);
    v = __builtin_amdgcn_cvt_pk_fp8_f32(d.z * scale, d.w * scale, v, true);
    o.w = v;
    dst[i] = o;
}

// Fused: weight cvt | hidden cvt | zero accumulators (ws poisoned each call).
__global__ void cvt_f32_fp8(const float4* __restrict__ srcW, int4* __restrict__ dstW,
                            const float4* __restrict__ srcH, int4* __restrict__ dstH,
                            int4* __restrict__ zr) {
    if (blockIdx.x < WBLK) {
        size_t i = (size_t)blockIdx.x * blockDim.x + threadIdx.x;
        cvt16(srcW, dstW, WSCALE, i);
    } else if (blockIdx.x < WBLK + HBLK) {
        size_t i = (size_t)(blockIdx.x - WBLK) * blockDim.x + threadIdx.x;
        cvt16(srcH, dstH, HSCALE, i);
    } else {
        int i = (blockIdx.x - WBLK - HBLK) * 256 + threadIdx.x;
        zr[i] = make_int4(0, 0, 0, 0);
    }
}

// ---------------- async global -> LDS (16 B per lane) ----------------
__device__ __forceinline__ void load_lds16(const uchar_t* g, uchar_t* l) {
    __builtin_amdgcn_global_load_lds(
        (const __attribute__((address_space(1))) unsigned int*)(const void*)g,
        (__attribute__((address_space(3))) unsigned int*)(void*)l,
        16, 0, 0);
}

// 32 B fragment = ONE contiguous LDS vector load (2 adjacent ds_read_b128,
// no repack movs).  The 32B granule swizzle keeps each fragment contiguous.
__device__ __forceinline__ i32x8 read_frag(const uchar_t* arr, int off) {
    return *reinterpret_cast<const i32x8*>(arr + off);
}

// ---------------- fused fp8 GEMM (MX, unit scales) + CE ---------------------
// 256x256 block tile, 8 waves (2M x 4N), 128x64 per wave, acc[8][4] = 128
// AGPR (unified-file accum side); ARCH side holds bfr[4] (32, live across
// one K-tile) + af pair (16, transient) + addressing < 128 (rounds 1/3 rule).
//
// 4-phase schedule per K-tile (round-4 post-mortem: one giant phase per tile
// phase-locked all 8 waves -> LDS reads and MFMA ran serial, 5772 cy/tile vs
// 2200 MFMA wall).  Small phases let wave skew overlap the two pipes:
//   phase p: { ds_read 2 A-frags (+4 B-frags in ph0)      -- feeds THIS phase
//              issue 3/3/2/0 global_load_lds of tile t+1  -- in flight across
//                                                            phases, vmcnt
//                                                            never hit early
//              s_barrier (asm, memory clobber) ; sched_barrier(0)
//              setprio(1) ; 8 MFMA ; setprio(0)
//              [ph3 only: vmcnt(0) -- drains tile-t+1 staging, issued >=2
//               phases (~1600 cy) earlier, effectively free]
//              s_barrier }
// Barriers are asm with "memory" clobber (round-2/4 proven) -- the bare
// __builtin_amdgcn_s_barrier() carries no memory-ordering edge and hipcc may
// move LDS ops across it (rule #18 analog); round 5's only structural diff
// from proven kernels was this, so it is hardened back.
//
// Buffer safety: reads of buf cur (ph0) follow the prior tile's vmcnt(0) +
// barrier; staging of buf (t+1)&1 issues only after the closing barrier of
// tile t-1, by which every wave's reads of that buffer were consumed (each
// read feeds an MFMA issued before that barrier).
//
// LDS swizzle (32B granule, round-0 proven): physical granule g of row r
// holds logical granule g ^ (r&3).  Write side stays linear for
// global_load_lds; each lane pre-swizzles its GLOBAL source granule.
__global__ __launch_bounds__(512, 2) void gemm_ce(
    const uchar_t* __restrict__ A,
    const uchar_t* __restrict__ B,
    const int* __restrict__ targets,
    float* __restrict__ sumexp,
    float* __restrict__ tgtlogit) {
    __shared__ alignas(32) uchar_t As[2][BM * BK];   // 2 x 32 KiB
    __shared__ alignas(32) uchar_t Bs[2][BN * BK];   // 2 x 32 KiB

    const int tid  = threadIdx.x;
    const int wave = tid >> 6;
    const int lane = tid & 63;
    const int quad = lane >> 4;
    const int l16  = lane & 15;
    const int wm   = (wave >> 2) * 128;  // wave grid: 2M x 4N, 128x64 each
    const int wn   = (wave & 3) * 64;

    const int m0 = blockIdx.x * BM;
    const int n0 = blockIdx.y * BN;

    // staging: per global_load_lds a wave writes 1024 B = 8 rows x 128 B,
    // linear in LDS.  Wave w stages A rows [w*32,+32) and B rows [w*32,+32),
    // 4+4 loads.  Lane L covers row sr=L>>3, 16B chunk c=L&7; it fetches
    // global granule (c>>1)^(sr&3), half c&1, so the linear LDS write lands
    // the granule-swizzled layout.
    const int srow = lane >> 3;
    const int scol = ((((lane & 7) >> 1) ^ (srow & 3)) << 5) + ((lane & 1) << 4);
    const uchar_t* Ag = A + (size_t)(m0 + wave * 32 + srow) * DDIM + scol;
    const uchar_t* Bg = B + (size_t)(n0 + wave * 32 + srow) * DDIM + scol;

    // fragment read offsets: row = (wm|wn) + f*16 + l16, r&3 == l16&3;
    // granule = quad, physical = quad ^ (l16&3), one 32B load per frag.
    const int gsw  = (quad ^ (l16 & 3)) << 5;
    const int aoff = (wm + l16) * BK + gsw;
    const int boff = (wn + l16) * BK + gsw;

    f32x4 acc[8][4];
    const f32x4 zero = {0.f, 0.f, 0.f, 0.f};
#pragma unroll
    for (int i = 0; i < 8; ++i)
#pragma unroll
        for (int j = 0; j < 4; ++j) acc[i][j] = zero;

#define BAR    asm volatile("s_barrier" ::: "memory")
#define SCHED0 __builtin_amdgcn_sched_barrier(0)
#define PRIO1  __builtin_amdgcn_s_setprio(1)
#define PRIO0  __builtin_amdgcn_s_setprio(0)
#define VM0    asm volatile("s_waitcnt vmcnt(0)" ::: "memory")

#define MFMA2(I, a0, a1)                                                       \
    _Pragma("unroll") for (int j_ = 0; j_ < 4; ++j_) {                         \
        acc[(I)][j_] = __builtin_amdgcn_mfma_scale_f32_16x16x128_f8f6f4(       \
            a0, bfr[j_], acc[(I)][j_], 0, 0, 0, SCALE_ONE, 0, SCALE_ONE);      \
        acc[(I) + 1][j_] = __builtin_amdgcn_mfma_scale_f32_16x16x128_f8f6f4(   \
            a1, bfr[j_], acc[(I) + 1][j_], 0, 0, 0, SCALE_ONE, 0, SCALE_ONE);  \
    }

    // prologue: stage K-tile 0 into buffer 0
    {
        uchar_t* a_ = &As[0][0] + (wave * 32) * BK;
        uchar_t* b_ = &Bs[0][0] + (wave * 32) * BK;
#pragma unroll
        for (int it = 0; it < 4; ++it) {
            load_lds16(Ag + (size_t)it * 8 * DDIM, a_ + it * 8 * BK);
            load_lds16(Bg + (size_t)it * 8 * DDIM, b_ + it * 8 * BK);
        }
    }
    VM0;
    BAR;

#pragma clang loop unroll(disable)
    for (int t = 0; t < NKT; ++t) {
        const uchar_t* as_ = &As[t & 1][0];
        const uchar_t* bs_ = &Bs[t & 1][0];
        uchar_t* an_ = &As[(t + 1) & 1][0] + (wave * 32) * BK;
        uchar_t* bn_ = &Bs[(t + 1) & 1][0] + (wave * 32) * BK;
        const int kn = (t + 1) * BK;
        const bool pf = (t < NKT - 1);
        i32x8 bfr[4], af0, af1;

        // ---- phase 0: B frags + A frags 0,1; stage 3 ----
#pragma unroll
        for (int j = 0; j < 4; ++j) bfr[j] = read_frag(bs_, boff + j * 2048);
        af0 = read_frag(as_, aoff);
        af1 = read_frag(as_, aoff + 2048);
        if (pf) {
            load_lds16(Ag + kn, an_);
            load_lds16(Ag + 8 * DDIM + kn, an_ + 8 * BK);
            load_lds16(Bg + kn, bn_);
        }
        BAR; SCHED0; PRIO1;
        MFMA2(0, af0, af1);
        PRIO0; BAR;

        // ---- phase 1: A frags 2,3; stage 3 ----
        af0 = read_frag(as_, aoff + 2 * 2048);
        af1 = read_frag(as_, aoff + 3 * 2048);
        if (pf) {
            load_lds16(Ag + 16 * DDIM + kn, an_ + 16 * BK);
            load_lds16(Ag + 24 * DDIM + kn, an_ + 24 * BK);
            load_lds16(Bg + 8 * DDIM + kn, bn_ + 8 * BK);
        }
        BAR; SCHED0; PRIO1;
        MFMA2(2, af0, af1);
        PRIO0; BAR;

        // ---- phase 2: A frags 4,5; stage 2 ----
        af0 = read_frag(as_, aoff + 4 * 2048);
        af1 = read_frag(as_, aoff + 5 * 2048);
        if (pf) {
            load_lds16(Bg + 16 * DDIM + kn, bn_ + 16 * BK);
            load_lds16(Bg + 24 * DDIM + kn, bn_ + 24 * BK);
        }
        BAR; SCHED0; PRIO1;
        MFMA2(4, af0, af1);
        PRIO0; BAR;

        // ---- phase 3: A frags 6,7; drain staging before closing barrier ----
        af0 = read_frag(as_, aoff + 6 * 2048);
        af1 = read_frag(as_, aoff + 7 * 2048);
        BAR; SCHED0; PRIO1;
        MFMA2(6, af0, af1);
        PRIO0;
        VM0;   // tile-t+1 staging (issued phases 0-2, ~1600+ cy ago) landed
        BAR;
    }

    // ---- epilogue: CE. C/D layout: row = quad*4 + reg, col = l16. ----
    // Pre-reduce the 4 N-waves' partial exp-sums in LDS -> 4x fewer global
    // atomics. LDS is dead after the sync.
    __syncthreads();
    float* sred = reinterpret_cast<float*>(&As[0][0]);   // [4][256] floats
#pragma unroll
    for (int i = 0; i < 8; ++i) {
#pragma unroll
        for (int r = 0; r < 4; ++r) {
            const int rloc = wm + i * 16 + quad * 4 + r;   // 0..255 in tile
            const int mg = m0 + rloc;
            const int t  = targets[mg];
            float p = 0.f;
#pragma unroll
            for (int j = 0; j < 4; ++j) {
                float v = acc[i][j][r] * INVSCALE;
                p += __expf(v);
                if (t == n0 + wn + j * 16 + l16) tgtlogit[mg] = v;
            }
            p += __shfl_xor(p, 1);
            p += __shfl_xor(p, 2);
            p += __shfl_xor(p, 4);
            p += __shfl_xor(p, 8);
            if (l16 == 0) sred[(wave & 3) * 256 + rloc] = p;
        }
    }
    __syncthreads();
    if (tid < 256) {
        float s = sred[tid] + sred[256 + tid] + sred[512 + tid] + sred[768 + tid];
        atomicAdd(&sumexp[m0 + tid], s);
    }

#undef BAR
#undef SCHED0
#undef PRIO1
#undef PRIO0
#undef VM0
#undef MFMA2
}

// ---------------- final reduction: loss = sum(log(sumexp)-tgt)/n_valid ------
__global__ void finalize(const float* __restrict__ sumexp,
                         const float* __restrict__ tgtlogit,
                         const int* __restrict__ targets,
                         float* __restrict__ out) {
    __shared__ float s_sum[16];
    __shared__ float s_cnt[16];
    float local = 0.f, cnt = 0.f;
    for (int t = threadIdx.x; t < MTOK; t += blockDim.x) {
        int tg = targets[t];
        if (tg != IGNORE_INDEX) {
            local += logf(sumexp[t]) - tgtlogit[t];
            cnt += 1.f;
        }
    }
#pragma unroll
    for (int o = 32; o > 0; o >>= 1) {
        local += __shfl_down(local, o);
        cnt   += __shfl_down(cnt, o);
    }
    const int wave = threadIdx.x >> 6, lane = threadIdx.x & 63;
    if (lane == 0) { s_sum[wave] = local; s_cnt[wave] = cnt; }
    __syncthreads();
    if (threadIdx.x == 0) {
        float ts = 0.f, tc = 0.f;
        for (int w = 0; w < (int)(blockDim.x >> 6); ++w) {
            ts += s_sum[w];
            tc += s_cnt[w];
        }
        out[0] = (tc > 0.f) ? (ts / tc) : ts;
    }
}

extern "C" void kernel_launch(void* const* d_in, const int* in_sizes, int n_in,
                              void* d_out, int out_size, void* d_ws,
                              size_t ws_size, hipStream_t stream) {
    const float* weight  = (const float*)d_in[0];   // [VOCAB][DDIM] fp32
    const float* hidden  = (const float*)d_in[1];   // [MTOK][DDIM] fp32
    const int*   targets = (const int*)d_in[2];     // [MTOK]
    float* out = (float*)d_out;

    const size_t wbytes = (size_t)VOCAB * DDIM;     // 65,536,000 (fp8)
    const size_t hbytes = (size_t)MTOK * DDIM;      // 16,777,216 (fp8)
    uchar_t* Wb = (uchar_t*)d_ws;
    uchar_t* Hb = (uchar_t*)d_ws + wbytes;
    float* sumexp   = (float*)((char*)d_ws + wbytes + hbytes);
    float* tgtlogit = sumexp + MTOK;

    // fp32 -> fp8 conversion for both tensors + zero accumulators, one launch
    cvt_f32_fp8<<<WBLK + HBLK + ZBLK, 256, 0, stream>>>(
        (const float4*)weight, (int4*)Wb, (const float4*)hidden, (int4*)Hb,
        (int4*)sumexp);

    dim3 grid(MTOK / BM, VOCAB / BN);   // 32 x 125
    gemm_ce<<<grid, 512, 0, stream>>>(Hb, Wb, targets, sumexp, tgtlogit);

    finalize<<<1, 1024, 0, stream>>>(sumexp, tgtlogit, targets, out);
}